// Round 3
// baseline (180.593 us; speedup 1.0000x reference)
//
#include <hip/hip_runtime.h>

// Raymarcher: R=16384 rays, 64 steps, K=32 prims, template (32,4,16,16,16) f32.
// One wave per ray, one lane per step. Alpha compositing via wave prefix-scan
// (exact: increments non-negative so iterated clip == min(prefix,1)).
// Per-(ray,prim) affine transform y=a+d*t precomputed in LDS.
// Template transposed to channel-last in d_ws -> 8 float4 corner loads.
// Round 3 fix: transpose grid was 4x too large (OOB read/write -> abort).

namespace {

constexpr float kDT = 1.0f / 64.0f;
constexpr int kVox = 32 * 4096;   // (k,z,y,x) index space = 131072

// ---- pre-pass: (k,c,z,y,x) -> (k,z,y,x,c) channel-last ----
__global__ __launch_bounds__(256) void transpose_tmpl(
    const float* __restrict__ tmpl, float* __restrict__ wsT)
{
    const int idx = blockIdx.x * 256 + threadIdx.x;     // < 131072
    const int k   = idx >> 12;
    const int rem = idx & 4095;
    const float* src = tmpl + k * 16384 + rem;
    float4 v;
    v.x = src[0];
    v.y = src[4096];
    v.z = src[8192];
    v.w = src[12288];
    ((float4*)wsT)[idx] = v;
}

template <bool T4>
__global__ __launch_bounds__(256) void raymarch2(
    const float* __restrict__ raypos,
    const float* __restrict__ raydir,
    const float* __restrict__ tminmax,
    const float* __restrict__ primpos,
    const float* __restrict__ primrot,
    const float* __restrict__ primscale,
    const float* __restrict__ tmpl,      // original layout (fallback path)
    const float* __restrict__ tmplT,     // channel-last layout (T4 path)
    float* __restrict__ out,
    int R)
{
    const int lane = threadIdx.x & 63;
    const int wid  = threadIdx.x >> 6;                 // wave in block, 0..3
    const int ray  = blockIdx.x * 4 + wid;             // R divisible by 4

    __shared__ float4 sA[4][32];   // a.xyz, tlo
    __shared__ float4 sD[4][32];   // d.xyz, thi

    const float rpx = raypos[ray * 3 + 0];
    const float rpy = raypos[ray * 3 + 1];
    const float rpz = raypos[ray * 3 + 2];
    const float rdx = raydir[ray * 3 + 0];
    const float rdy = raydir[ray * 3 + 1];
    const float rdz = raydir[ray * 3 + 2];
    const float tmin = tminmax[ray * 2 + 0];
    const float tmax = tminmax[ray * 2 + 1];

    if (lane < 32) {
        const int k = lane;
        const float ox = rpx - primpos[k * 3 + 0];
        const float oy = rpy - primpos[k * 3 + 1];
        const float oz = rpz - primpos[k * 3 + 2];
        float a[3], d[3];
        float lo = -1e30f, hi = 1e30f;
        #pragma unroll
        for (int i = 0; i < 3; ++i) {
            const float r0 = primrot[k * 9 + 3 * i + 0];
            const float r1 = primrot[k * 9 + 3 * i + 1];
            const float r2 = primrot[k * 9 + 3 * i + 2];
            const float sci = primscale[k * 3 + i];
            a[i] = (r0 * ox + r1 * oy + r2 * oz) * sci;
            d[i] = (r0 * rdx + r1 * rdy + r2 * rdz) * sci;
            const float inv = 1.0f / d[i];
            const float tA = (-1.001f - a[i]) * inv;
            const float tB = ( 1.001f - a[i]) * inv;
            lo = fmaxf(lo, fminf(tA, tB));
            hi = fminf(hi, fmaxf(tA, tB));
        }
        sA[wid][k] = make_float4(a[0], a[1], a[2], lo);
        sD[wid][k] = make_float4(d[0], d[1], d[2], hi);
    }
    __syncthreads();

    const float t = fmaf((float)lane, kDT, tmin);
    const bool tvalid = (t < tmax);

    float s0 = 0.f, s1 = 0.f, s2 = 0.f, s3 = 0.f;

    for (int k = 0; k < 32; ++k) {
        const float4 A = sA[wid][k];
        const float4 D = sD[wid][k];
        const bool maybe = tvalid && (t >= A.w) && (t <= D.w);
        if (__ballot(maybe) == 0ull) continue;
        if (maybe) {
            const float y0 = fmaf(D.x, t, A.x);
            const float y1 = fmaf(D.y, t, A.y);
            const float y2 = fmaf(D.z, t, A.z);
            if (fabsf(y0) <= 1.0f && fabsf(y1) <= 1.0f && fabsf(y2) <= 1.0f) {
                const float gz = (y0 + 1.0f) * 7.5f;
                const float gy = (y1 + 1.0f) * 7.5f;
                const float gx = (y2 + 1.0f) * 7.5f;
                const int iz = (int)fminf(floorf(gz), 14.0f);
                const int iy = (int)fminf(floorf(gy), 14.0f);
                const int ix = (int)fminf(floorf(gx), 14.0f);
                const float fz = fminf(gz - (float)iz, 1.0f);
                const float fy = fminf(gy - (float)iy, 1.0f);
                const float fx = fminf(gx - (float)ix, 1.0f);
                const float oz_ = 1.0f - fz, oy_ = 1.0f - fy, ox_ = 1.0f - fx;
                const float w000 = oz_ * oy_ * ox_;
                const float w001 = oz_ * oy_ * fx;
                const float w010 = oz_ * fy  * ox_;
                const float w011 = oz_ * fy  * fx;
                const float w100 = fz  * oy_ * ox_;
                const float w101 = fz  * oy_ * fx;
                const float w110 = fz  * fy  * ox_;
                const float w111 = fz  * fy  * fx;
                if (T4) {
                    const float* tp = tmplT + ((k * 4096 + iz * 256 + iy * 16 + ix) << 2);
                    const float4 c000 = *(const float4*)(tp + 0);
                    const float4 c001 = *(const float4*)(tp + 4);
                    const float4 c010 = *(const float4*)(tp + 64);
                    const float4 c011 = *(const float4*)(tp + 68);
                    const float4 c100 = *(const float4*)(tp + 1024);
                    const float4 c101 = *(const float4*)(tp + 1028);
                    const float4 c110 = *(const float4*)(tp + 1088);
                    const float4 c111 = *(const float4*)(tp + 1092);
                    s0 += w000*c000.x + w001*c001.x + w010*c010.x + w011*c011.x
                        + w100*c100.x + w101*c101.x + w110*c110.x + w111*c111.x;
                    s1 += w000*c000.y + w001*c001.y + w010*c010.y + w011*c011.y
                        + w100*c100.y + w101*c101.y + w110*c110.y + w111*c111.y;
                    s2 += w000*c000.z + w001*c001.z + w010*c010.z + w011*c011.z
                        + w100*c100.z + w101*c101.z + w110*c110.z + w111*c111.z;
                    s3 += w000*c000.w + w001*c001.w + w010*c010.w + w011*c011.w
                        + w100*c100.w + w101*c101.w + w110*c110.w + w111*c111.w;
                } else {
                    const float* tp = tmpl + k * 16384 + iz * 256 + iy * 16 + ix;
                    float* sacc[4] = {&s0, &s1, &s2, &s3};
                    #pragma unroll
                    for (int c = 0; c < 4; ++c) {
                        const float* tc = tp + c * 4096;
                        *sacc[c] += w000 * tc[0]   + w001 * tc[1]
                                  + w010 * tc[16]  + w011 * tc[17]
                                  + w100 * tc[256] + w101 * tc[257]
                                  + w110 * tc[272] + w111 * tc[273];
                    }
                }
            }
        }
    }

    // Alpha compositing: inclusive prefix scan of a = salpha*DT*valid over the
    // 64 steps (lanes); alpha_i = min(psum_i, 1) (exact since a >= 0).
    const float a = s3 * kDT * (tvalid ? 1.0f : 0.0f);
    float psum = a;
    #pragma unroll
    for (int m = 1; m < 64; m <<= 1) {
        const float n = __shfl_up(psum, m);
        if (lane >= m) psum += n;
    }
    const float alpha_i    = fminf(psum, 1.0f);
    const float alpha_prev = fminf(psum - a, 1.0f);
    const float contrib    = alpha_i - alpha_prev;

    float r0 = s0 * contrib;
    float r1 = s1 * contrib;
    float r2 = s2 * contrib;
    #pragma unroll
    for (int m = 1; m < 64; m <<= 1) {
        r0 += __shfl_xor(r0, m);
        r1 += __shfl_xor(r1, m);
        r2 += __shfl_xor(r2, m);
    }
    const float alpha_end = __shfl(alpha_i, 63);

    if (lane == 0) {
        out[0 * R + ray] = r0;
        out[1 * R + ray] = r1;
        out[2 * R + ray] = r2;
        out[3 * R + ray] = alpha_end;
        out[4 * R + ray] = r0;
        out[5 * R + ray] = r1;
        out[6 * R + ray] = r2;
        out[7 * R + ray] = alpha_end;
    }
}

} // namespace

extern "C" void kernel_launch(void* const* d_in, const int* in_sizes, int n_in,
                              void* d_out, int out_size, void* d_ws, size_t ws_size,
                              hipStream_t stream) {
    const float* raypos    = (const float*)d_in[0];
    const float* raydir    = (const float*)d_in[1];
    const float* tminmax   = (const float*)d_in[2];
    const float* primpos   = (const float*)d_in[3];
    const float* primrot   = (const float*)d_in[4];
    const float* primscale = (const float*)d_in[5];
    const float* tmpl      = (const float*)d_in[6];
    float* out = (float*)d_out;

    const int R = in_sizes[0] / 3;   // 16384
    const size_t tmplBytes = (size_t)kVox * 4 * sizeof(float);  // 2 MiB

    if (ws_size >= tmplBytes) {
        float* wsT = (float*)d_ws;
        transpose_tmpl<<<dim3(kVox / 256), dim3(256), 0, stream>>>(tmpl, wsT);
        raymarch2<true><<<dim3(R / 4), dim3(256), 0, stream>>>(
            raypos, raydir, tminmax, primpos, primrot, primscale, tmpl, wsT, out, R);
    } else {
        raymarch2<false><<<dim3(R / 4), dim3(256), 0, stream>>>(
            raypos, raydir, tminmax, primpos, primrot, primscale, tmpl, nullptr, out, R);
    }
}